// Round 1
// baseline (988.945 us; speedup 1.0000x reference)
//
#include <hip/hip_runtime.h>

#define Hd 64
#define Nn 1024

__device__ __forceinline__ float siluf(float v) { return v / (1.0f + expf(-v)); }

__device__ __forceinline__ float bcastf(float v, int l) {
    return __int_as_float(__builtin_amdgcn_readlane(__float_as_int(v), l));
}

// Kernel A: ha = h@Wa^T + eb1 ; hb = h@Wb^T ; hn1 = h@nw1[:, :64]^T + nb1
__global__ __launch_bounds__(256) void precompute_kernel(
    const float* __restrict__ h, const float* __restrict__ ew1,
    const float* __restrict__ eb1, const float* __restrict__ nw1,
    const float* __restrict__ nb1, float* __restrict__ ha,
    float* __restrict__ hb, float* __restrict__ hn1)
{
    int t = blockIdx.x * 256 + threadIdx.x;   // 0 .. 3*65536-1
    int which = t >> 16;
    int rem = t & 65535;
    int i = rem >> 6, o = rem & 63;
    const float* hrow = h + i * Hd;
    const float* wrow;
    float acc;
    if (which == 0)      { wrow = ew1 + o * 130;      acc = eb1[o]; }
    else if (which == 1) { wrow = ew1 + o * 130 + 64; acc = 0.0f;   }
    else                 { wrow = nw1 + o * 128;      acc = nb1[o]; }
    #pragma unroll
    for (int k = 0; k < 64; ++k) acc = fmaf(hrow[k], wrow[k], acc);
    if (which == 0)      ha[rem]  = acc;
    else if (which == 1) hb[rem]  = acc;
    else                 hn1[rem] = acc;
}

// Kernel B: fused edge pipeline. One block per i; wave w handles j in [256w, 256w+256).
__global__ __launch_bounds__(256) void edge_kernel(
    const float* __restrict__ x, const float* __restrict__ Lp,
    const float* __restrict__ ha, const float* __restrict__ hb,
    const float* __restrict__ ew1, const float* __restrict__ ew2,
    const float* __restrict__ eb2, const float* __restrict__ chw,
    const float* __restrict__ chb, const float* __restrict__ aw,
    const float* __restrict__ ab, const float* __restrict__ cww,
    float* __restrict__ agg, float* __restrict__ delta)
{
    __shared__ float xs[3 * Nn];
    __shared__ float sagg[4][64];
    __shared__ float sdel[4][3];

    const int i = blockIdx.x;
    const int tid = threadIdx.x;
    const int w = tid >> 6, lane = tid & 63;

    for (int t = tid; t < 3 * Nn; t += 256) xs[t] = x[t];
    __syncthreads();

    const float L = Lp[0];
    const float invL = 1.0f / L;

    // per-lane weight rows (static-indexed -> registers)
    float w2[64], wc[64];
    #pragma unroll
    for (int k4 = 0; k4 < 16; ++k4) {
        float4 v2 = *reinterpret_cast<const float4*>(ew2 + lane * 64 + k4 * 4);
        w2[4 * k4 + 0] = v2.x; w2[4 * k4 + 1] = v2.y;
        w2[4 * k4 + 2] = v2.z; w2[4 * k4 + 3] = v2.w;
        float4 vc = *reinterpret_cast<const float4*>(chw + lane * 64 + k4 * 4);
        wc[4 * k4 + 0] = vc.x; wc[4 * k4 + 1] = vc.y;
        wc[4 * k4 + 2] = vc.z; wc[4 * k4 + 3] = vc.w;
    }

    const float hak  = ha[i * 64 + lane];                       // includes eb1
    const float wrk  = ew1[lane * 130 + 128] + ew1[lane * 130 + 129];
    const float eb2k = eb2[lane], chbk = chb[lane];
    const float awk  = aw[lane],  cwwk = cww[lane];
    const float ab0  = ab[0];
    const float xi0 = xs[i * 3 + 0], xi1 = xs[i * 3 + 1], xi2 = xs[i * 3 + 2];

    float aggk = 0.0f, dd0 = 0.0f, dd1 = 0.0f, dd2 = 0.0f;

    const int j0 = w * 256, j1 = j0 + 256;
    for (int j = j0; j < j1; ++j) {
        const float hbj = hb[j * 64 + lane];

        float a0 = xi0 - xs[j * 3 + 0];
        float a1 = xi1 - xs[j * 3 + 1];
        float a2 = xi2 - xs[j * 3 + 2];
        float d0 = a0 - L * floorf(fmaf(a0, invL, 0.5f));
        float d1 = a1 - L * floorf(fmaf(a1, invL, 0.5f));
        float d2 = a2 - L * floorf(fmaf(a2, invL, 0.5f));
        float radial = d0 * d0 + d1 * d1 + d2 * d2;
        float cinv = 1.0f / (sqrtf(radial + 1e-8f) + 1.0f);

        float pre = hak + hbj + radial * wrk;
        float tv = siluf(pre);

        float acc = eb2k;
        #pragma unroll
        for (int k = 0; k < 64; ++k) acc = fmaf(bcastf(tv, k), w2[k], acc);
        float e = siluf(acc);

        float p = e * awk;
        #pragma unroll
        for (int off = 32; off; off >>= 1) p += __shfl_xor(p, off);
        float att = 1.0f / (1.0f + expf(-(p + ab0)));
        e *= att;

        float acc2 = chbk;
        #pragma unroll
        for (int k = 0; k < 64; ++k) acc2 = fmaf(bcastf(e, k), wc[k], acc2);
        float chv = siluf(acc2);

        float q = chv * cwwk;
        #pragma unroll
        for (int off = 32; off; off >>= 1) q += __shfl_xor(q, off);
        float wv = tanhf(q) * 10.0f;   // COORDS_RANGE

        dd0 = fmaf(d0 * cinv, wv, dd0);
        dd1 = fmaf(d1 * cinv, wv, dd1);
        dd2 = fmaf(d2 * cinv, wv, dd2);
        aggk += e;
    }

    sagg[w][lane] = aggk;
    if (lane == 0) { sdel[w][0] = dd0; sdel[w][1] = dd1; sdel[w][2] = dd2; }
    __syncthreads();
    if (w == 0) {
        agg[i * 64 + lane] = sagg[0][lane] + sagg[1][lane] + sagg[2][lane] + sagg[3][lane];
        if (lane < 3)
            delta[i * 3 + lane] = sdel[0][lane] + sdel[1][lane] + sdel[2][lane] + sdel[3][lane];
    }
}

// Kernel C1: sp = silu(hn1 + agg@nw1[:,64:].T) ; plus x_new
__global__ __launch_bounds__(256) void node1_kernel(
    const float* __restrict__ hn1, const float* __restrict__ agg,
    const float* __restrict__ nw1, const float* __restrict__ x,
    const float* __restrict__ delta, const float* __restrict__ Lp,
    float* __restrict__ sp, float* __restrict__ outx)
{
    int b = blockIdx.x;
    if (b < 256) {
        int t = b * 256 + threadIdx.x;
        int i = t >> 6, o = t & 63;
        const float* arow = agg + i * 64;
        const float* wrow = nw1 + o * 128 + 64;
        float acc = hn1[t];
        #pragma unroll
        for (int k = 0; k < 64; ++k) acc = fmaf(arow[k], wrow[k], acc);
        sp[t] = siluf(acc);
    } else {
        int i = (b - 256) * 256 + threadIdx.x;
        if (i < Nn) {
            float L = Lp[0];
            #pragma unroll
            for (int d = 0; d < 3; ++d) {
                float v = x[i * 3 + d] + delta[i * 3 + d];
                outx[i * 3 + d] = v - L * floorf(v / L);
            }
        }
    }
}

// Kernel C2: h_new = h + sp@nw2.T + nb2
__global__ __launch_bounds__(256) void node2_kernel(
    const float* __restrict__ h, const float* __restrict__ sp,
    const float* __restrict__ nw2, const float* __restrict__ nb2,
    float* __restrict__ outh)
{
    int t = blockIdx.x * 256 + threadIdx.x;
    int i = t >> 6, o = t & 63;
    const float* srow = sp + i * 64;
    const float* wrow = nw2 + o * 64;
    float acc = h[t] + nb2[o];
    #pragma unroll
    for (int k = 0; k < 64; ++k) acc = fmaf(srow[k], wrow[k], acc);
    outh[t] = acc;
}

extern "C" void kernel_launch(void* const* d_in, const int* in_sizes, int n_in,
                              void* d_out, int out_size, void* d_ws, size_t ws_size,
                              hipStream_t stream) {
    const float* h   = (const float*)d_in[0];
    const float* x   = (const float*)d_in[1];
    const float* Lp  = (const float*)d_in[2];
    const float* ew1 = (const float*)d_in[3];
    const float* eb1 = (const float*)d_in[4];
    const float* ew2 = (const float*)d_in[5];
    const float* eb2 = (const float*)d_in[6];
    const float* nw1 = (const float*)d_in[7];
    const float* nb1 = (const float*)d_in[8];
    const float* nw2 = (const float*)d_in[9];
    const float* nb2 = (const float*)d_in[10];
    const float* chw = (const float*)d_in[11];
    const float* chb = (const float*)d_in[12];
    const float* cww = (const float*)d_in[13];
    const float* aw  = (const float*)d_in[14];
    const float* ab  = (const float*)d_in[15];

    float* ws    = (float*)d_ws;
    float* ha    = ws;             // 65536
    float* hb    = ws + 65536;     // 65536
    float* hn1   = ws + 131072;    // 65536
    float* agg   = ws + 196608;    // 65536
    float* sp    = ws + 262144;    // 65536
    float* delta = ws + 327680;    // 3072

    float* outh = (float*)d_out;       // 65536
    float* outx = outh + 65536;        // 3072

    precompute_kernel<<<768, 256, 0, stream>>>(h, ew1, eb1, nw1, nb1, ha, hb, hn1);
    edge_kernel<<<1024, 256, 0, stream>>>(x, Lp, ha, hb, ew1, ew2, eb2, chw, chb,
                                          aw, ab, cww, agg, delta);
    node1_kernel<<<260, 256, 0, stream>>>(hn1, agg, nw1, x, delta, Lp, sp, outx);
    node2_kernel<<<256, 256, 0, stream>>>(h, sp, nw2, nb2, outh);
}

// Round 2
// 183.039 us; speedup vs baseline: 5.4029x; 5.4029x over previous
//
#include <hip/hip_runtime.h>

#define Nn 1024
#define Hd 64

typedef __attribute__((ext_vector_type(8))) short short8v;
typedef __attribute__((ext_vector_type(4))) float floatx4;

__device__ __forceinline__ float fsilu(float v) { return v / (1.0f + __expf(-v)); }
__device__ __forceinline__ float fsig(float v)  { return 1.0f / (1.0f + __expf(-v)); }
__device__ __forceinline__ float ftanhf(float v){ return 1.0f - 2.0f / (__expf(2.0f * v) + 1.0f); }

__device__ __forceinline__ unsigned f2bf1(float f) {
    unsigned u = __float_as_uint(f);
    return (u + 0x7FFFu + ((u >> 16) & 1u)) >> 16;
}
__device__ __forceinline__ unsigned f2bf2(float lo, float hi) {
    return f2bf1(lo) | (f2bf1(hi) << 16);
}

// Kernel A: ha = h@Wa^T + eb1 ; hb = h@Wb^T ; hn1 = h@nw1[:, :64]^T + nb1
__global__ __launch_bounds__(256) void precompute_kernel(
    const float* __restrict__ h, const float* __restrict__ ew1,
    const float* __restrict__ eb1, const float* __restrict__ nw1,
    const float* __restrict__ nb1, float* __restrict__ ha,
    float* __restrict__ hb, float* __restrict__ hn1)
{
    int t = blockIdx.x * 256 + threadIdx.x;
    int which = t >> 16;
    int rem = t & 65535;
    int i = rem >> 6, o = rem & 63;
    const float* hrow = h + i * Hd;
    const float* wrow;
    float acc;
    if (which == 0)      { wrow = ew1 + o * 130;      acc = eb1[o]; }
    else if (which == 1) { wrow = ew1 + o * 130 + 64; acc = 0.0f;   }
    else                 { wrow = nw1 + o * 128;      acc = nb1[o]; }
    #pragma unroll
    for (int k = 0; k < 64; ++k) acc = fmaf(hrow[k], wrow[k], acc);
    if (which == 0)      ha[rem]  = acc;
    else if (which == 1) hb[rem]  = acc;
    else                 hn1[rem] = acc;
}

// Edge pipeline via MFMA. 256 blocks x 512 threads; block owns 4 i's, loops j in 16 chunks of 64.
// M = 256 edge rows (m = ii*64 + jj), K = N = 64.
__global__ __launch_bounds__(512) void edge_mfma_kernel(
    const float* __restrict__ x, const float* __restrict__ Lp,
    const float* __restrict__ ha, const float* __restrict__ hb,
    const float* __restrict__ ew1, const float* __restrict__ ew2,
    const float* __restrict__ eb2, const float* __restrict__ chw,
    const float* __restrict__ chb, const float* __restrict__ aw,
    const float* __restrict__ ab, const float* __restrict__ cww,
    float* __restrict__ agg, float* __restrict__ delta)
{
    __shared__ int4 Tbuf[256 * 8];    // 256 rows x 64 bf16, XOR-swizzled (unit ^ (row&7))
    __shared__ int4 Ebuf[256 * 8];
    __shared__ float xs[Nn * 3];
    __shared__ float dxs[2][3][256];  // coord_diff * cinv, double-buffered per chunk
    __shared__ float has[4 * 64];
    __shared__ float wrs[64];
    __shared__ float redagg[8][64];
    __shared__ float sdel[8][3];

    const int tid = threadIdx.x;
    const int wave = tid >> 6, lane = tid & 63;
    const int g = lane >> 4, lr = lane & 15;
    const int i0 = blockIdx.x * 4;
    const int mt0 = wave * 2;

    for (int idx = tid; idx < Nn * 3; idx += 512) xs[idx] = x[idx];
    if (tid < 256) has[tid] = ha[i0 * 64 + tid];
    if (tid < 64)  wrs[tid] = ew1[tid * 130 + 128] + ew1[tid * 130 + 129];

    // B fragments (ew2, chw) packed to bf16 in registers, straight from global.
    // frag: col n = l&15 (+16*nt), k = kt*32 + (l>>4)*8 + e  -> 8 contiguous of row n.
    short8v bw2[2][4], bwc[2][4];
    #pragma unroll
    for (int kt = 0; kt < 2; ++kt)
      #pragma unroll
      for (int nt = 0; nt < 4; ++nt) {
        int n = nt * 16 + lr;
        int k0 = kt * 32 + g * 8;
        float4 lo = *(const float4*)(ew2 + n * 64 + k0);
        float4 hi = *(const float4*)(ew2 + n * 64 + k0 + 4);
        union { short8v s; unsigned u[4]; } pk;
        pk.u[0] = f2bf2(lo.x, lo.y); pk.u[1] = f2bf2(lo.z, lo.w);
        pk.u[2] = f2bf2(hi.x, hi.y); pk.u[3] = f2bf2(hi.z, hi.w);
        bw2[kt][nt] = pk.s;
        lo = *(const float4*)(chw + n * 64 + k0);
        hi = *(const float4*)(chw + n * 64 + k0 + 4);
        pk.u[0] = f2bf2(lo.x, lo.y); pk.u[1] = f2bf2(lo.z, lo.w);
        pk.u[2] = f2bf2(hi.x, hi.y); pk.u[3] = f2bf2(hi.z, hi.w);
        bwc[kt][nt] = pk.s;
      }

    float eb2r[4], awr[4], chbr[4], cwwr[4];
    #pragma unroll
    for (int nt = 0; nt < 4; ++nt) {
      int n = nt * 16 + lr;
      eb2r[nt] = eb2[n]; awr[nt] = aw[n]; chbr[nt] = chb[n]; cwwr[nt] = cww[n];
    }
    const float ab0 = ab[0];
    const float L = Lp[0], invL = 1.0f / L;

    const int bm = tid >> 1;         // build-T row 0..255
    const int bhalf = tid & 1;       // which 32 of k
    const int bii = bm >> 6, bjj = bm & 63;

    float aggp[4] = {0.f, 0.f, 0.f, 0.f};
    float dp[3] = {0.f, 0.f, 0.f};
    const floatx4 fzero = {0.f, 0.f, 0.f, 0.f};

    __syncthreads();

    const float xi0 = xs[(i0 + bii) * 3 + 0];
    const float xi1 = xs[(i0 + bii) * 3 + 1];
    const float xi2 = xs[(i0 + bii) * 3 + 2];

    for (int jc = 0; jc < 16; ++jc) {
      // ---- build T = silu(ha + hb + radial*wr) -> Tbuf (bf16, swizzled) ----
      int j = jc * 64 + bjj;
      float a0 = xi0 - xs[j * 3 + 0];
      float a1 = xi1 - xs[j * 3 + 1];
      float a2 = xi2 - xs[j * 3 + 2];
      float d0 = a0 - L * floorf(fmaf(a0, invL, 0.5f));
      float d1 = a1 - L * floorf(fmaf(a1, invL, 0.5f));
      float d2 = a2 - L * floorf(fmaf(a2, invL, 0.5f));
      float radial = d0 * d0 + d1 * d1 + d2 * d2;
      float cinv = 1.0f / (sqrtf(radial + 1e-8f) + 1.0f);
      if (bhalf == 0) {
        dxs[jc & 1][0][bm] = d0 * cinv;
        dxs[jc & 1][1][bm] = d1 * cinv;
        dxs[jc & 1][2][bm] = d2 * cinv;
      }
      const float* hbrow = hb + j * 64 + bhalf * 32;
      #pragma unroll
      for (int c2 = 0; c2 < 4; ++c2) {
        int k0 = bhalf * 32 + c2 * 8;
        float4 hlo = *(const float4*)(hbrow + c2 * 8);
        float4 hhi = *(const float4*)(hbrow + c2 * 8 + 4);
        float f[8] = {hlo.x, hlo.y, hlo.z, hlo.w, hhi.x, hhi.y, hhi.z, hhi.w};
        unsigned u[4];
        #pragma unroll
        for (int e2 = 0; e2 < 4; ++e2) {
          float plo = has[bii * 64 + k0 + 2 * e2]     + f[2 * e2]     + radial * wrs[k0 + 2 * e2];
          float phi = has[bii * 64 + k0 + 2 * e2 + 1] + f[2 * e2 + 1] + radial * wrs[k0 + 2 * e2 + 1];
          u[e2] = f2bf2(fsilu(plo), fsilu(phi));
        }
        int unit = (bm * 8 + (k0 >> 3)) ^ (bm & 7);
        Tbuf[unit] = make_int4(u[0], u[1], u[2], u[3]);
      }
      __syncthreads();   // T ready; also: all Ebuf reads of prev chunk done

      // ---- GEMM1: D1 = T @ ew2^T ----
      floatx4 acc[2][4];
      #pragma unroll
      for (int mi = 0; mi < 2; ++mi)
        #pragma unroll
        for (int nt = 0; nt < 4; ++nt) acc[mi][nt] = fzero;
      #pragma unroll
      for (int kt = 0; kt < 2; ++kt) {
        short8v af[2];
        #pragma unroll
        for (int mi = 0; mi < 2; ++mi) {
          int row = (mt0 + mi) * 16 + lr;
          int unit = (row * 8 + kt * 4 + g) ^ (row & 7);
          af[mi] = *(const short8v*)&Tbuf[unit];
        }
        #pragma unroll
        for (int mi = 0; mi < 2; ++mi)
          #pragma unroll
          for (int nt = 0; nt < 4; ++nt)
            acc[mi][nt] = __builtin_amdgcn_mfma_f32_16x16x32_bf16(af[mi], bw2[kt][nt], acc[mi][nt], 0, 0, 0);
      }

      // ---- epilogue 1: silu, att, agg, edge -> Ebuf ----
      float p[2][4];
      #pragma unroll
      for (int mi = 0; mi < 2; ++mi) { p[mi][0] = p[mi][1] = p[mi][2] = p[mi][3] = 0.f; }
      #pragma unroll
      for (int mi = 0; mi < 2; ++mi)
        #pragma unroll
        for (int nt = 0; nt < 4; ++nt)
          #pragma unroll
          for (int r = 0; r < 4; ++r) {
            float s = fsilu(acc[mi][nt][r] + eb2r[nt]);
            acc[mi][nt][r] = s;
            p[mi][r] = fmaf(s, awr[nt], p[mi][r]);
          }
      #pragma unroll
      for (int mi = 0; mi < 2; ++mi)
        #pragma unroll
        for (int r = 0; r < 4; ++r) {
          float v = p[mi][r];
          v += __shfl_xor(v, 1); v += __shfl_xor(v, 2);
          v += __shfl_xor(v, 4); v += __shfl_xor(v, 8);
          p[mi][r] = fsig(v + ab0);
        }
      unsigned short* Eb = (unsigned short*)Ebuf;
      #pragma unroll
      for (int mi = 0; mi < 2; ++mi)
        #pragma unroll
        for (int nt = 0; nt < 4; ++nt)
          #pragma unroll
          for (int r = 0; r < 4; ++r) {
            float e = acc[mi][nt][r] * p[mi][r];
            aggp[nt] += e;                     // fp32 agg accumulation
            int m = (mt0 + mi) * 16 + g * 4 + r;
            int n = nt * 16 + lr;
            Eb[(m * 64 + n) ^ ((m & 7) << 3)] = (unsigned short)f2bf1(e);
          }
      __syncthreads();   // edge ready

      // ---- GEMM2: D2 = edge @ chw^T ----
      #pragma unroll
      for (int mi = 0; mi < 2; ++mi)
        #pragma unroll
        for (int nt = 0; nt < 4; ++nt) acc[mi][nt] = fzero;
      #pragma unroll
      for (int kt = 0; kt < 2; ++kt) {
        short8v af[2];
        #pragma unroll
        for (int mi = 0; mi < 2; ++mi) {
          int row = (mt0 + mi) * 16 + lr;
          int unit = (row * 8 + kt * 4 + g) ^ (row & 7);
          af[mi] = *(const short8v*)&Ebuf[unit];
        }
        #pragma unroll
        for (int mi = 0; mi < 2; ++mi)
          #pragma unroll
          for (int nt = 0; nt < 4; ++nt)
            acc[mi][nt] = __builtin_amdgcn_mfma_f32_16x16x32_bf16(af[mi], bwc[kt][nt], acc[mi][nt], 0, 0, 0);
      }

      // ---- epilogue 2: silu, tanh dot, delta ----
      float q[2][4];
      #pragma unroll
      for (int mi = 0; mi < 2; ++mi) { q[mi][0] = q[mi][1] = q[mi][2] = q[mi][3] = 0.f; }
      #pragma unroll
      for (int mi = 0; mi < 2; ++mi)
        #pragma unroll
        for (int nt = 0; nt < 4; ++nt)
          #pragma unroll
          for (int r = 0; r < 4; ++r) {
            float c = fsilu(acc[mi][nt][r] + chbr[nt]);
            q[mi][r] = fmaf(c, cwwr[nt], q[mi][r]);
          }
      #pragma unroll
      for (int mi = 0; mi < 2; ++mi)
        #pragma unroll
        for (int r = 0; r < 4; ++r) {
          float v = q[mi][r];
          v += __shfl_xor(v, 1); v += __shfl_xor(v, 2);
          v += __shfl_xor(v, 4); v += __shfl_xor(v, 8);
          float wv = ftanhf(v) * 10.0f;
          int m = (mt0 + mi) * 16 + g * 4 + r;
          dp[0] = fmaf(dxs[jc & 1][0][m], wv, dp[0]);
          dp[1] = fmaf(dxs[jc & 1][1][m], wv, dp[1]);
          dp[2] = fmaf(dxs[jc & 1][2][m], wv, dp[2]);
        }
    }

    // ---- final reductions: per-wave partials -> agg, delta ----
    #pragma unroll
    for (int nt = 0; nt < 4; ++nt) {
      aggp[nt] += __shfl_xor(aggp[nt], 16);
      aggp[nt] += __shfl_xor(aggp[nt], 32);
    }
    if (lane < 16) {
      #pragma unroll
      for (int nt = 0; nt < 4; ++nt) redagg[wave][nt * 16 + lane] = aggp[nt];
    }
    #pragma unroll
    for (int d = 0; d < 3; ++d) {
      dp[d] += __shfl_xor(dp[d], 16);
      dp[d] += __shfl_xor(dp[d], 32);
    }
    if (lane == 0) { sdel[wave][0] = dp[0]; sdel[wave][1] = dp[1]; sdel[wave][2] = dp[2]; }
    __syncthreads();
    if (tid < 256) {
      int a = tid >> 6, n = tid & 63;
      agg[(i0 + a) * 64 + n] = redagg[2 * a][n] + redagg[2 * a + 1][n];
    }
    if (tid < 12) {
      int a = tid / 3, d = tid % 3;
      delta[(i0 + a) * 3 + d] = sdel[2 * a][d] + sdel[2 * a + 1][d];
    }
}

// Kernel C1: sp = silu(hn1 + agg@nw1[:,64:].T) ; plus x_new
__global__ __launch_bounds__(256) void node1_kernel(
    const float* __restrict__ hn1, const float* __restrict__ agg,
    const float* __restrict__ nw1, const float* __restrict__ x,
    const float* __restrict__ delta, const float* __restrict__ Lp,
    float* __restrict__ sp, float* __restrict__ outx)
{
    int b = blockIdx.x;
    if (b < 256) {
        int t = b * 256 + threadIdx.x;
        int i = t >> 6, o = t & 63;
        const float* arow = agg + i * 64;
        const float* wrow = nw1 + o * 128 + 64;
        float acc = hn1[t];
        #pragma unroll
        for (int k = 0; k < 64; ++k) acc = fmaf(arow[k], wrow[k], acc);
        sp[t] = fsilu(acc);
    } else {
        int i = (b - 256) * 256 + threadIdx.x;
        if (i < Nn) {
            float L = Lp[0];
            #pragma unroll
            for (int d = 0; d < 3; ++d) {
                float v = x[i * 3 + d] + delta[i * 3 + d];
                outx[i * 3 + d] = v - L * floorf(v / L);
            }
        }
    }
}

// Kernel C2: h_new = h + sp@nw2.T + nb2
__global__ __launch_bounds__(256) void node2_kernel(
    const float* __restrict__ h, const float* __restrict__ sp,
    const float* __restrict__ nw2, const float* __restrict__ nb2,
    float* __restrict__ outh)
{
    int t = blockIdx.x * 256 + threadIdx.x;
    int i = t >> 6, o = t & 63;
    const float* srow = sp + i * 64;
    const float* wrow = nw2 + o * 64;
    float acc = h[t] + nb2[o];
    #pragma unroll
    for (int k = 0; k < 64; ++k) acc = fmaf(srow[k], wrow[k], acc);
    outh[t] = acc;
}

extern "C" void kernel_launch(void* const* d_in, const int* in_sizes, int n_in,
                              void* d_out, int out_size, void* d_ws, size_t ws_size,
                              hipStream_t stream) {
    const float* h   = (const float*)d_in[0];
    const float* x   = (const float*)d_in[1];
    const float* Lp  = (const float*)d_in[2];
    const float* ew1 = (const float*)d_in[3];
    const float* eb1 = (const float*)d_in[4];
    const float* ew2 = (const float*)d_in[5];
    const float* eb2 = (const float*)d_in[6];
    const float* nw1 = (const float*)d_in[7];
    const float* nb1 = (const float*)d_in[8];
    const float* nw2 = (const float*)d_in[9];
    const float* nb2 = (const float*)d_in[10];
    const float* chw = (const float*)d_in[11];
    const float* chb = (const float*)d_in[12];
    const float* cww = (const float*)d_in[13];
    const float* aw  = (const float*)d_in[14];
    const float* ab  = (const float*)d_in[15];

    float* ws    = (float*)d_ws;
    float* ha    = ws;             // 65536
    float* hb    = ws + 65536;     // 65536
    float* hn1   = ws + 131072;    // 65536
    float* agg   = ws + 196608;    // 65536
    float* sp    = ws + 262144;    // 65536
    float* delta = ws + 327680;    // 3072

    float* outh = (float*)d_out;       // 65536
    float* outx = outh + 65536;        // 3072

    precompute_kernel<<<768, 256, 0, stream>>>(h, ew1, eb1, nw1, nb1, ha, hb, hn1);
    edge_mfma_kernel<<<256, 512, 0, stream>>>(x, Lp, ha, hb, ew1, ew2, eb2, chw, chb,
                                              aw, ab, cww, agg, delta);
    node1_kernel<<<260, 256, 0, stream>>>(hn1, agg, nw1, x, delta, Lp, sp, outx);
    node2_kernel<<<256, 256, 0, stream>>>(h, sp, nw2, nb2, outh);
}